// Round 2
// baseline (356.723 us; speedup 1.0000x reference)
//
#include <hip/hip_runtime.h>
#include <hip/hip_bf16.h>
#include <math.h>
#include <type_traits>

// MoE: E=16 experts, D=768, H=768, T=32*197=6304 tokens. ALL fp32 in/out
// (reference dtypes); bf16 used internally for MFMA only.
#define T_TOK 6304
#define DMODEL 768
#define NEXP 16

typedef __bf16 bf16x8 __attribute__((ext_vector_type(8)));
typedef float f32x4 __attribute__((ext_vector_type(4)));

__device__ __forceinline__ unsigned short f2bf(float f) {
    __hip_bfloat16 b = __float2bfloat16(f);   // round-to-nearest-even
    return __builtin_bit_cast(unsigned short, b);
}
__device__ __forceinline__ unsigned int pack2(float lo, float hi) {
    return (unsigned int)f2bf(lo) | ((unsigned int)f2bf(hi) << 16);
}
// 16 fp32 from global -> 16 bf16 into LDS (two uint4 writes)
__device__ __forceinline__ void cvt16(const float* __restrict__ s,
                                      unsigned short* __restrict__ d) {
    const float4* sv = (const float4*)s;
    float4 v0 = sv[0], v1 = sv[1], v2 = sv[2], v3 = sv[3];
    uint4 w0, w1;
    w0.x = pack2(v0.x, v0.y); w0.y = pack2(v0.z, v0.w);
    w0.z = pack2(v1.x, v1.y); w0.w = pack2(v1.z, v1.w);
    w1.x = pack2(v2.x, v2.y); w1.y = pack2(v2.z, v2.w);
    w1.z = pack2(v3.x, v3.y); w1.w = pack2(v3.z, v3.w);
    ((uint4*)d)[0] = w0;
    ((uint4*)d)[1] = w1;
}

// ---------------- gate: fp64 dot for argmax stability vs np fp32 ref ----------------
__global__ __launch_bounds__(256) void gate_kernel(
    const float* __restrict__ x, const float* __restrict__ Wg,
    const float* __restrict__ bg, int* __restrict__ cnt, int* __restrict__ list)
{
    int t = blockIdx.x * 4 + (threadIdx.x >> 6);   // one wave per token; 6304 = 4*1576
    int lane = threadIdx.x & 63;
    float xr[12];
#pragma unroll
    for (int i = 0; i < 12; ++i)
        xr[i] = x[(size_t)t * DMODEL + i * 64 + lane];
    double best = -1e300; int bi = 0;
#pragma unroll
    for (int e = 0; e < NEXP; ++e) {
        double p = 0.0;
#pragma unroll
        for (int i = 0; i < 12; ++i)
            p += (double)xr[i] * (double)Wg[e * DMODEL + i * 64 + lane];
#pragma unroll
        for (int off = 32; off > 0; off >>= 1)
            p += __shfl_xor(p, off, 64);
        p += (double)bg[e];
        if (p > best) { best = p; bi = e; }   // strict >: first-max, matches np argmax
    }
    if (lane == 0) {
        int pos = atomicAdd(&cnt[bi], 1);
        list[bi * T_TOK + pos] = t;
    }
}

// ---------------- gathered expert GEMM: out[t] = act(in[t] @ W[e]^T + bias[e]) -------
// BM=64 x BN=128 x BK=64, 4 waves; MFMA 16x16x32 bf16.
// A frag: m=lane&15, k=(lane>>4)*8+j ; C/D: col=lane&15, row=(lane>>4)*4+reg (m89/m91).
template<int GELU, typename TIN, typename TOUT>
__global__ __launch_bounds__(256) void expert_layer(
    const TIN* __restrict__ in,     // float (x) or unsigned short (bf16 h)
    const float* __restrict__ W,    // [E,768,768] fp32, row n contiguous in k
    const float* __restrict__ bias, // [E,768] fp32
    const int* __restrict__ cnt,
    const int* __restrict__ list,
    TOUT* __restrict__ outp)        // unsigned short (bf16 h) or float (y)
{
    constexpr int BM = 64, BN = 128, BK = 64;
    constexpr int LDK = BK + 8;     // pad 64->72: only 2-way bank aliasing (free, m136)
    __shared__ __align__(16) unsigned short At[BM][LDK];
    __shared__ __align__(16) unsigned short Bt[BN][LDK];
    __shared__ int toks[BM];

    const int e  = blockIdx.z;
    const int c  = cnt[e];
    const int m0 = blockIdx.y * BM;
    if (m0 >= c) return;            // uniform early-exit (before any sync)
    const int n0  = blockIdx.x * BN;
    const int tid = threadIdx.x;
    const int lane = tid & 63;
    const int w    = tid >> 6;

    if (tid < BM) {
        int mi = m0 + tid;
        toks[tid] = list[e * T_TOK + (mi < c ? mi : m0)];  // clamp pad rows to valid token
    }

    const float* Wb = W + (size_t)e * DMODEL * DMODEL;

    f32x4 acc[8];
#pragma unroll
    for (int j = 0; j < 8; ++j) acc[j] = (f32x4){0.f, 0.f, 0.f, 0.f};

    const int ar = tid >> 2;            // A row 0..63
    const int ak = (tid & 3) * 16;      // A k base: 16 elements
    const int br = tid >> 1;            // B row 0..127
    const int bk = (tid & 1) * 32;      // B k base: 32 elements
    const int l15 = lane & 15;
    const int q8  = (lane >> 4) * 8;

    for (int k0 = 0; k0 < DMODEL; k0 += BK) {
        __syncthreads();                // also covers toks[] on first iteration
        // stage A: 64x64, convert to bf16 if fp32 source
        if constexpr (std::is_same<TIN, float>::value) {
            cvt16(in + (size_t)toks[ar] * DMODEL + k0 + ak, &At[ar][ak]);
        } else {
            const uint4* src = (const uint4*)(in + (size_t)toks[ar] * DMODEL + k0 + ak);
            *(uint4*)&At[ar][ak]     = src[0];
            *(uint4*)&At[ar][ak + 8] = src[1];
        }
        // stage B: 128x64 fp32 weights -> bf16
        {
            const float* src = Wb + (size_t)(n0 + br) * DMODEL + k0 + bk;
            cvt16(src,      &Bt[br][bk]);
            cvt16(src + 16, &Bt[br][bk + 16]);
        }
        __syncthreads();
#pragma unroll
        for (int kk = 0; kk < BK; kk += 32) {
            bf16x8 a = *(const bf16x8*)&At[w * 16 + l15][kk + q8];
#pragma unroll
            for (int j = 0; j < 8; ++j) {
                bf16x8 b = *(const bf16x8*)&Bt[j * 16 + l15][kk + q8];
                acc[j] = __builtin_amdgcn_mfma_f32_16x16x32_bf16(a, b, acc[j], 0, 0, 0);
            }
        }
    }

    // epilogue: bias (+ exact GELU), scatter rows
    const int q = lane >> 4;
#pragma unroll
    for (int j = 0; j < 8; ++j) {
        int col = n0 + j * 16 + l15;
        float bv = bias[e * DMODEL + col];
#pragma unroll
        for (int r = 0; r < 4; ++r) {
            int mrow = w * 16 + q * 4 + r;
            if (m0 + mrow < c) {
                float v = acc[j][r] + bv;
                if (GELU) v = 0.5f * v * (1.f + erff(v * 0.70710678118654752f));
                size_t idx = (size_t)toks[mrow] * DMODEL + col;
                if constexpr (std::is_same<TOUT, float>::value)
                    outp[idx] = v;
                else
                    outp[idx] = f2bf(v);
            }
        }
    }
}

extern "C" void kernel_launch(void* const* d_in, const int* in_sizes, int n_in,
                              void* d_out, int out_size, void* d_ws, size_t ws_size,
                              hipStream_t stream)
{
    const float* x  = (const float*)d_in[0];
    const float* W1 = (const float*)d_in[1];
    const float* b1 = (const float*)d_in[2];
    const float* W2 = (const float*)d_in[3];
    const float* b2 = (const float*)d_in[4];
    const float* Wg = (const float*)d_in[5];
    const float* bg = (const float*)d_in[6];
    float* out = (float*)d_out;

    char* ws   = (char*)d_ws;
    int*  cnt  = (int*)ws;                               // 64 B
    int*  list = (int*)(ws + 256);                       // 16*6304*4 = 403456 B
    unsigned short* h = (unsigned short*)(ws + 404480);  // 6304*768*2 = 9682944 B (bf16)

    hipMemsetAsync(cnt, 0, NEXP * sizeof(int), stream);
    gate_kernel<<<dim3(T_TOK / 4), dim3(256), 0, stream>>>(x, Wg, bg, cnt, list);

    dim3 grid(DMODEL / 128, (T_TOK + 63) / 64, NEXP);    // (6, 99, 16); idle tiles early-exit
    expert_layer<1, float, unsigned short><<<grid, dim3(256), 0, stream>>>(x, W1, b1, cnt, list, h);
    expert_layer<0, unsigned short, float><<<grid, dim3(256), 0, stream>>>(h, W2, b2, cnt, list, out);
}

// Round 3
// 352.894 us; speedup vs baseline: 1.0108x; 1.0108x over previous
//
#include <hip/hip_runtime.h>
#include <hip/hip_bf16.h>
#include <math.h>
#include <type_traits>

// MoE: E=16, D=H=768, T=6304 tokens; fp32 in/out, bf16 internally for MFMA.
#define T_TOK 6304
#define DMODEL 768
#define NEXP 16

typedef __bf16 bf16x8 __attribute__((ext_vector_type(8)));
typedef float f32x4 __attribute__((ext_vector_type(4)));

__device__ __forceinline__ unsigned short f2bf(float f) {
    __hip_bfloat16 b = __float2bfloat16(f);   // RNE
    return __builtin_bit_cast(unsigned short, b);
}
__device__ __forceinline__ unsigned int pack2(float lo, float hi) {
    return (unsigned int)f2bf(lo) | ((unsigned int)f2bf(hi) << 16);
}

// ---------------- streaming fp32 -> bf16 convert ----------------
__global__ __launch_bounds__(256) void cvt_kernel(const float4* __restrict__ s,
                                                  uint2* __restrict__ d, int n4) {
    int i = blockIdx.x * 256 + threadIdx.x;
    if (i < n4) {
        float4 v = s[i];
        d[i] = make_uint2(pack2(v.x, v.y), pack2(v.z, v.w));
    }
}

// ---------------- gate: thread = (token, expert); fp64 accum; no shuffles -----------
__global__ __launch_bounds__(256) void gate_kernel(
    const float* __restrict__ x, const float* __restrict__ Wg,
    const float* __restrict__ bg, int* __restrict__ cnt, int* __restrict__ list)
{
    __shared__ double lg[16][17];
    const int tt = threadIdx.x >> 4;          // token within block (16)
    const int e  = threadIdx.x & 15;          // expert (16)
    const int t  = blockIdx.x * 16 + tt;      // 6304 = 394 * 16 exactly
    const float4* xr = (const float4*)(x + (size_t)t * DMODEL);
    const float4* wr = (const float4*)(Wg + (size_t)e * DMODEL);
    double s0 = 0, s1 = 0, s2 = 0, s3 = 0;    // 4 independent chains (ILP)
#pragma unroll 4
    for (int i = 0; i < DMODEL / 4; ++i) {
        float4 a = xr[i], w = wr[i];
        s0 += (double)a.x * (double)w.x;
        s1 += (double)a.y * (double)w.y;
        s2 += (double)a.z * (double)w.z;
        s3 += (double)a.w * (double)w.w;
    }
    lg[tt][e] = (s0 + s1) + (s2 + s3);
    __syncthreads();
    if (e == 0) {
        double best = -1e300; int bi = 0;
#pragma unroll
        for (int k = 0; k < NEXP; ++k) {
            double v = lg[tt][k] + (double)bg[k];
            if (v > best) { best = v; bi = k; }   // strict >: first-max (np argmax)
        }
        int pos = atomicAdd(&cnt[bi], 1);
        list[bi * T_TOK + pos] = t;
    }
}

// ---------------- gathered expert GEMM with register-prefetch pipeline --------------
// BM=64 x BN=128 x BK=64, 4 waves. Wave w: rows (w&1)*32 (2 m-frags), cols
// (w>>1)*64 (4 n-frags) -> 8 MFMA per kk-step, 6 ds_read_b128.
// MFMA 16x16x32 bf16: A m=lane&15,k=(lane>>4)*8+j ; C/D col=lane&15,row=(lane>>4)*4+reg.
template<int GELU, typename TA, typename TW, typename TOUT>
__global__ __launch_bounds__(256) void expert_layer(
    const TA* __restrict__ in,      // ushort (bf16) or float
    const TW* __restrict__ W,       // ushort (bf16 pre-cvt) or float, [E,768,768]
    const float* __restrict__ bias, // [E,768] fp32
    const int* __restrict__ cnt,
    const int* __restrict__ list,
    TOUT* __restrict__ outp)        // ushort (bf16 h) or float
{
    constexpr int BM = 64, BN = 128, BK = 64, LDK = 72; // +8 pad: 2-way bank alias only
    constexpr bool A_F32 = std::is_same<TA, float>::value;
    constexpr bool W_F32 = std::is_same<TW, float>::value;
    __shared__ __align__(16) unsigned short At[BM][LDK];
    __shared__ __align__(16) unsigned short Bt[BN][LDK];
    __shared__ int toks[BM];

    const int bx = blockIdx.x;          // e fastest: lin%8 == e%8 -> XCD affinity for W
    const int e  = bx & 15, nb = bx >> 4;
    const int c  = cnt[e];
    const int m0 = blockIdx.y * BM;
    if (m0 >= c) return;                // uniform exit before any sync
    const int n0  = nb * BN;
    const int tid = threadIdx.x, lane = tid & 63, w = tid >> 6;

    if (tid < BM) {
        int mi = m0 + tid;
        toks[tid] = list[e * T_TOK + (mi < c ? mi : m0)];  // clamp pads to valid token
    }

    // staging roles
    const int ar = tid >> 2, ak = (tid & 3) * 16;   // A: 16 elems/thread
    const int br = tid >> 1, bk = (tid & 1) * 32;   // B: 32 elems/thread
    const int ma = m0 + ar;
    const int tok_a = list[e * T_TOK + (ma < c ? ma : m0)]; // direct (avoid toks race)
    const TA* asrc = in + (size_t)tok_a * DMODEL + ak;
    const TW* bsrc = W + (size_t)e * DMODEL * DMODEL + (size_t)(n0 + br) * DMODEL + bk;

    const int rg = w & 1, cg = w >> 1;
    const int l15 = lane & 15, q8 = (lane >> 4) * 8, q = lane >> 4;

    f32x4 acc[2][4];
#pragma unroll
    for (int i = 0; i < 2; ++i)
#pragma unroll
        for (int j = 0; j < 4; ++j) acc[i][j] = (f32x4){0.f, 0.f, 0.f, 0.f};

    uint4 pa[2], pb[4];     // bf16 prefetch regs
    float4 fa[4], fb[8];    // fp32 prefetch regs (unused in bf16 instantiation)

    auto load_tiles = [&](int k0) {
        if constexpr (A_F32) {
            const float4* s = (const float4*)(asrc + k0);
            fa[0] = s[0]; fa[1] = s[1]; fa[2] = s[2]; fa[3] = s[3];
        } else {
            const uint4* s = (const uint4*)(asrc + k0);
            pa[0] = s[0]; pa[1] = s[1];
        }
        if constexpr (W_F32) {
            const float4* s = (const float4*)(bsrc + k0);
            fb[0] = s[0]; fb[1] = s[1]; fb[2] = s[2]; fb[3] = s[3];
            fb[4] = s[4]; fb[5] = s[5]; fb[6] = s[6]; fb[7] = s[7];
        } else {
            const uint4* s = (const uint4*)(bsrc + k0);
            pb[0] = s[0]; pb[1] = s[1]; pb[2] = s[2]; pb[3] = s[3];
        }
    };
    auto store_tiles = [&]() {
        if constexpr (A_F32) {
            uint4 w0, w1;
            w0.x = pack2(fa[0].x, fa[0].y); w0.y = pack2(fa[0].z, fa[0].w);
            w0.z = pack2(fa[1].x, fa[1].y); w0.w = pack2(fa[1].z, fa[1].w);
            w1.x = pack2(fa[2].x, fa[2].y); w1.y = pack2(fa[2].z, fa[2].w);
            w1.z = pack2(fa[3].x, fa[3].y); w1.w = pack2(fa[3].z, fa[3].w);
            *(uint4*)&At[ar][ak] = w0; *(uint4*)&At[ar][ak + 8] = w1;
        } else {
            *(uint4*)&At[ar][ak] = pa[0]; *(uint4*)&At[ar][ak + 8] = pa[1];
        }
        if constexpr (W_F32) {
#pragma unroll
            for (int h2 = 0; h2 < 4; ++h2) {
                uint4 wv;
                wv.x = pack2(fb[2*h2].x, fb[2*h2].y);
                wv.y = pack2(fb[2*h2].z, fb[2*h2].w);
                wv.z = pack2(fb[2*h2+1].x, fb[2*h2+1].y);
                wv.w = pack2(fb[2*h2+1].z, fb[2*h2+1].w);
                *(uint4*)&Bt[br][bk + h2 * 8] = wv;
            }
        } else {
            *(uint4*)&Bt[br][bk]      = pb[0];
            *(uint4*)&Bt[br][bk + 8]  = pb[1];
            *(uint4*)&Bt[br][bk + 16] = pb[2];
            *(uint4*)&Bt[br][bk + 24] = pb[3];
        }
    };

    load_tiles(0);                       // prologue
#pragma unroll 1
    for (int it = 0; it < DMODEL / BK; ++it) {
        __syncthreads();                 // prev consumers done (also covers toks[])
        store_tiles();
        __syncthreads();                 // tiles ready
        if (it + 1 < DMODEL / BK) load_tiles((it + 1) * BK);  // overlap w/ MFMA below
#pragma unroll
        for (int kk = 0; kk < BK; kk += 32) {
            bf16x8 a0 = *(const bf16x8*)&At[rg * 32 + l15][kk + q8];
            bf16x8 a1 = *(const bf16x8*)&At[rg * 32 + 16 + l15][kk + q8];
#pragma unroll
            for (int j = 0; j < 4; ++j) {
                bf16x8 b = *(const bf16x8*)&Bt[cg * 64 + j * 16 + l15][kk + q8];
                acc[0][j] = __builtin_amdgcn_mfma_f32_16x16x32_bf16(a0, b, acc[0][j], 0, 0, 0);
                acc[1][j] = __builtin_amdgcn_mfma_f32_16x16x32_bf16(a1, b, acc[1][j], 0, 0, 0);
            }
        }
    }

    // epilogue: bias (+ exact GELU), scatter
#pragma unroll
    for (int i = 0; i < 2; ++i) {
#pragma unroll
        for (int j = 0; j < 4; ++j) {
            int col = n0 + cg * 64 + j * 16 + l15;
            float bv = bias[e * DMODEL + col];
#pragma unroll
            for (int r = 0; r < 4; ++r) {
                int mrow = rg * 32 + i * 16 + q * 4 + r;
                if (m0 + mrow < c) {
                    float v = acc[i][j][r] + bv;
                    if (GELU) v = 0.5f * v * (1.f + erff(v * 0.70710678118654752f));
                    size_t idx = (size_t)toks[mrow] * DMODEL + col;
                    if constexpr (std::is_same<TOUT, float>::value) outp[idx] = v;
                    else outp[idx] = f2bf(v);
                }
            }
        }
    }
}

extern "C" void kernel_launch(void* const* d_in, const int* in_sizes, int n_in,
                              void* d_out, int out_size, void* d_ws, size_t ws_size,
                              hipStream_t stream)
{
    const float* x  = (const float*)d_in[0];
    const float* W1 = (const float*)d_in[1];
    const float* b1 = (const float*)d_in[2];
    const float* W2 = (const float*)d_in[3];
    const float* b2 = (const float*)d_in[4];
    const float* Wg = (const float*)d_in[5];
    const float* bg = (const float*)d_in[6];
    float* out = (float*)d_out;

    char* ws   = (char*)d_ws;
    int*  cnt  = (int*)ws;                                // 64 B
    int*  list = (int*)(ws + 256);                        // 403,456 B
    unsigned short* h = (unsigned short*)(ws + 403712);   // 9,682,944 B

    hipMemsetAsync(cnt, 0, NEXP * sizeof(int), stream);
    gate_kernel<<<dim3(T_TOK / 16), dim3(256), 0, stream>>>(x, Wg, bg, cnt, list);

    dim3 grid(6 * NEXP, (T_TOK + 63) / 64);               // x: e fastest (XCD affinity)
    const size_t need = 57518336;
    if (ws_size >= need) {
        unsigned short* xb  = (unsigned short*)(ws + 10086656);
        unsigned short* w1b = (unsigned short*)(ws + 19769600);
        unsigned short* w2b = (unsigned short*)(ws + 38643968);
        cvt_kernel<<<dim3(9216), dim3(256), 0, stream>>>((const float4*)W1, (uint2*)w1b, 2359296);
        cvt_kernel<<<dim3(9216), dim3(256), 0, stream>>>((const float4*)W2, (uint2*)w2b, 2359296);
        cvt_kernel<<<dim3(4728), dim3(256), 0, stream>>>((const float4*)x,  (uint2*)xb, 1210368);
        expert_layer<1, unsigned short, unsigned short, unsigned short>
            <<<grid, dim3(256), 0, stream>>>(xb, w1b, b1, cnt, list, h);
        expert_layer<0, unsigned short, unsigned short, float>
            <<<grid, dim3(256), 0, stream>>>(h, w2b, b2, cnt, list, out);
    } else {  // fallback: fused fp32->bf16 staging (round-2 semantics)
        expert_layer<1, float, float, unsigned short>
            <<<grid, dim3(256), 0, stream>>>(x, W1, b1, cnt, list, h);
        expert_layer<0, unsigned short, float, float>
            <<<grid, dim3(256), 0, stream>>>(h, W2, b2, cnt, list, out);
    }
}